// Round 1
// baseline (58.943 us; speedup 1.0000x reference)
//
#include <hip/hip_runtime.h>
#include <hip/hip_bf16.h>

// Sizes (fixed by the problem)
#define BATCH   16384
#define NUM_TAGS 1024
#define DIM     64
#define HIDDEN  128
// z = [q(64), mu(64), a(64), p12, p13, p23] -> 195

typedef __attribute__((ext_vector_type(8))) short bf16x8;
typedef __attribute__((ext_vector_type(4))) float f32x4;

// ---------------------------------------------------------------------------
// prep: convert S_emb (f32 [1024][64]) into bf16 B-fragment-linear layout:
//   Spack[((KS*4 + nf)*64 + lane)*8 + j] = bf16( S[KS*32 + (lane>>4)*8 + j][nf*16 + (lane&15)] )
// so the GEMM can load each B fragment as one 16B dwordx4.
// ---------------------------------------------------------------------------
__global__ __launch_bounds__(256) void prep_spack(const float* __restrict__ S,
                                                  unsigned short* __restrict__ Spack)
{
    int tid = blockIdx.x * 256 + threadIdx.x;   // 0..65535
    int j  = tid & 7;
    int l  = (tid >> 3) & 63;
    int nf = (tid >> 9) & 3;
    int ks = tid >> 11;                          // 0..31
    int k  = ks * 32 + (l >> 4) * 8 + j;
    int d  = nf * 16 + (l & 15);
    float v = S[k * 64 + d];
    unsigned u = __builtin_bit_cast(unsigned, v);
    unsigned r = (u + 0x7FFFu + ((u >> 16) & 1u)) >> 16;   // RNE to bf16
    Spack[tid] = (unsigned short)r;
}

// ---------------------------------------------------------------------------
// gemm_mu: musum[ksp][b][d] = sum_{k in half ksp} T[b][k] * S[k][d]   (bf16 MFMA, f32 acc)
//          cnt[ksp][b]      = sum_{k in half ksp} T[b][k]             (MFMA vs all-ones B)
// One wave per (16-row M-tile, K-half). 2048 waves total.
// ---------------------------------------------------------------------------
__global__ __launch_bounds__(256) void gemm_mu(const int* __restrict__ T,
                                               const unsigned short* __restrict__ Spack,
                                               float* __restrict__ musum,
                                               float* __restrict__ cnt)
{
    const int lane = threadIdx.x & 63;
    const int wid  = threadIdx.x >> 6;
    const int gw   = blockIdx.x * 4 + wid;   // 0..2047
    const int mt   = gw >> 1;                // M-tile 0..1023
    const int ksp  = gw & 1;                 // K half
    const int g    = lane >> 4;              // 0..3
    const int rl   = lane & 15;

    f32x4 acc0{}, acc1{}, acc2{}, acc3{}, accc{};
    bf16x8 ones;
#pragma unroll
    for (int j = 0; j < 8; ++j) ones[j] = (short)0x3F80;

    // A loads: lane reads 8 consecutive ints of its row at its k-slot
    const int* tptr = T + (mt * 16 + rl) * 1024 + g * 8 + ksp * 512;
    const unsigned short* spbase = Spack + (size_t)(ksp * 16 * 4) * 64 * 8 + lane * 8;

#pragma unroll 4
    for (int ks = 0; ks < 16; ++ks) {
        int4 t0 = *(const int4*)(tptr + ks * 32);
        int4 t1 = *(const int4*)(tptr + ks * 32 + 4);
        bf16x8 af;
        af[0] = t0.x ? (short)0x3F80 : (short)0;
        af[1] = t0.y ? (short)0x3F80 : (short)0;
        af[2] = t0.z ? (short)0x3F80 : (short)0;
        af[3] = t0.w ? (short)0x3F80 : (short)0;
        af[4] = t1.x ? (short)0x3F80 : (short)0;
        af[5] = t1.y ? (short)0x3F80 : (short)0;
        af[6] = t1.z ? (short)0x3F80 : (short)0;
        af[7] = t1.w ? (short)0x3F80 : (short)0;

        const unsigned short* sp = spbase + (size_t)ks * 4 * 64 * 8;
        bf16x8 b0 = *(const bf16x8*)(sp);
        bf16x8 b1 = *(const bf16x8*)(sp + 64 * 8);
        bf16x8 b2 = *(const bf16x8*)(sp + 2 * 64 * 8);
        bf16x8 b3 = *(const bf16x8*)(sp + 3 * 64 * 8);

        acc0 = __builtin_amdgcn_mfma_f32_16x16x32_bf16(af, b0, acc0, 0, 0, 0);
        acc1 = __builtin_amdgcn_mfma_f32_16x16x32_bf16(af, b1, acc1, 0, 0, 0);
        acc2 = __builtin_amdgcn_mfma_f32_16x16x32_bf16(af, b2, acc2, 0, 0, 0);
        acc3 = __builtin_amdgcn_mfma_f32_16x16x32_bf16(af, b3, acc3, 0, 0, 0);
        accc = __builtin_amdgcn_mfma_f32_16x16x32_bf16(af, ones, accc, 0, 0, 0);
    }

    // D layout: col = lane&15, row = (lane>>4)*4 + reg
    float* mo = musum + (size_t)ksp * (BATCH * DIM);
    float* co = cnt + ksp * BATCH;
#pragma unroll
    for (int r = 0; r < 4; ++r) {
        int b = mt * 16 + g * 4 + r;
        mo[b * 64 + rl]      = acc0[r];
        mo[b * 64 + 16 + rl] = acc1[r];
        mo[b * 64 + 32 + rl] = acc2[r];
        mo[b * 64 + 48 + rl] = acc3[r];
        if (rl == 0) co[b] = accc[r];
    }
}

// ---------------------------------------------------------------------------
// tail: per row: mu = musum/cnt, q gather, a = df@W_diff + b_diff,
//       p12/p13/p23, e = relu(z@W_fc + b_fc), p = sigmoid(e@W_out + b_out)
// One block (256 thr) per 16 rows.
// ---------------------------------------------------------------------------
__global__ __launch_bounds__(256) void tail_kernel(
    const int* __restrict__ questions, const float* __restrict__ dfeat,
    const float* __restrict__ Qemb,
    const float* __restrict__ Wdiff, const float* __restrict__ bdiff,
    const float* __restrict__ Wfc, const float* __restrict__ bfc,
    const float* __restrict__ Wout, const float* __restrict__ bout,
    const float* __restrict__ musum, const float* __restrict__ cntbuf,
    float* __restrict__ out_e, float* __restrict__ out_p)
{
    __shared__ float z[16][200];       // 195 used
    __shared__ float epart[16][128];

    const int tid  = threadIdx.x;
    const int wid  = tid >> 6;
    const int lane = tid & 63;
    const int rowbase = blockIdx.x * 16;

    // Phase A: wave w builds z rows w*4 .. w*4+3
#pragma unroll
    for (int i = 0; i < 4; ++i) {
        int rl = wid * 4 + i;
        int b  = rowbase + rl;
        float c  = cntbuf[b] + cntbuf[BATCH + b];
        float mu = (musum[(size_t)b * 64 + lane] + musum[(size_t)BATCH * 64 + (size_t)b * 64 + lane]) / c;
        int   qi = questions[b];
        float q  = Qemb[(size_t)qi * 64 + lane];
        float d0 = dfeat[b * 3 + 0], d1 = dfeat[b * 3 + 1], d2 = dfeat[b * 3 + 2];
        float a  = bdiff[lane] + d0 * Wdiff[lane] + d1 * Wdiff[64 + lane] + d2 * Wdiff[128 + lane];
        z[rl][lane]       = q;
        z[rl][64 + lane]  = mu;
        z[rl][128 + lane] = a;
        float s12 = q * mu, s13 = q * a, s23 = mu * a;
#pragma unroll
        for (int off = 32; off; off >>= 1) {
            s12 += __shfl_xor(s12, off);
            s13 += __shfl_xor(s13, off);
            s23 += __shfl_xor(s23, off);
        }
        if (lane == 0) { z[rl][192] = s12; z[rl][193] = s13; z[rl][194] = s23; }
    }
    __syncthreads();

    // Phase B: thread = (h = tid&127, rr = tid>>7), 8 row-accumulators so
    // W_fc is loaded once per block.
    const int h  = tid & 127;
    const int rr = tid >> 7;
    float acc[8];
    float bb = bfc[h];
#pragma unroll
    for (int r = 0; r < 8; ++r) acc[r] = bb;
    for (int j = 0; j < 195; ++j) {
        float w = Wfc[j * 128 + h];
#pragma unroll
        for (int r = 0; r < 8; ++r) acc[r] += z[rr * 8 + r][j] * w;
    }
    float wo = Wout[h];
#pragma unroll
    for (int r = 0; r < 8; ++r) {
        float e = acc[r] > 0.f ? acc[r] : 0.f;
        out_e[(size_t)(rowbase + rr * 8 + r) * 128 + h] = e;
        epart[rr * 8 + r][h] = e * wo;
    }
    __syncthreads();

    // Phase C: wave w reduces rows w*4 .. w*4+3 -> p
#pragma unroll
    for (int i = 0; i < 4; ++i) {
        int rl = wid * 4 + i;
        float v = epart[rl][lane] + epart[rl][64 + lane];
#pragma unroll
        for (int off = 32; off; off >>= 1) v += __shfl_xor(v, off);
        if (lane == 0) {
            float x = v + bout[0];
            out_p[rowbase + rl] = 1.f / (1.f + expf(-x));
        }
    }
}

// ---------------------------------------------------------------------------
extern "C" void kernel_launch(void* const* d_in, const int* in_sizes, int n_in,
                              void* d_out, int out_size, void* d_ws, size_t ws_size,
                              hipStream_t stream)
{
    const int*   questions = (const int*)d_in[0];
    const int*   T         = (const int*)d_in[1];
    const float* dfeat     = (const float*)d_in[2];
    const float* Qemb      = (const float*)d_in[3];
    const float* Semb      = (const float*)d_in[4];
    const float* Wdiff     = (const float*)d_in[5];
    const float* bdiff     = (const float*)d_in[6];
    const float* Wfc       = (const float*)d_in[7];
    const float* bfc       = (const float*)d_in[8];
    const float* Wout      = (const float*)d_in[9];
    const float* bout      = (const float*)d_in[10];

    char* ws = (char*)d_ws;
    unsigned short* Spack = (unsigned short*)ws;                       // 128 KiB
    float* musum = (float*)(ws + (1 << 20));                           // 2 x 4 MiB
    float* cnt   = (float*)(ws + (1 << 20) + (8 << 20));               // 2 x 64 KiB

    float* out_e = (float*)d_out;
    float* out_p = out_e + (size_t)BATCH * HIDDEN;

    hipLaunchKernelGGL(prep_spack, dim3(256), dim3(256), 0, stream, Semb, Spack);
    hipLaunchKernelGGL(gemm_mu, dim3(512), dim3(256), 0, stream, T, Spack, musum, cnt);
    hipLaunchKernelGGL(tail_kernel, dim3(1024), dim3(256), 0, stream,
                       questions, dfeat, Qemb, Wdiff, bdiff, Wfc, bfc, Wout, bout,
                       musum, cnt, out_e, out_p);
}

// Round 3
// 28.404 us; speedup vs baseline: 2.0751x; 2.0751x over previous
//
#include <hip/hip_runtime.h>
#include <hip/hip_bf16.h>

#define BATCH   16384
#define NTAGS   1024
#define DIM     64
#define HID     128

typedef __attribute__((ext_vector_type(8))) short bf16x8;
typedef __attribute__((ext_vector_type(4))) float f32x4;

__device__ __forceinline__ unsigned short f2bf(float v) {
    unsigned u = __builtin_bit_cast(unsigned, v);
    return (unsigned short)((u + 0x7FFFu + ((u >> 16) & 1u)) >> 16);   // RNE
}

// ---------------------------------------------------------------------------
// prep: pack S_emb (f32 [1024][64]) and Wfc[0:192] (f32 [195][128]) into
// bf16 B-fragment-linear layouts so GEMM B loads are single dwordx4.
//   frag layout: col = lane&15, k = (lane>>4)*8 + j
// Spack: [ks(32)][nf(4)][lane(64)][j(8)]   (65536 elems)
// Wp:    [kt(6)][ct(8)][lane(64)][j(8)]    (24576 elems)
// ---------------------------------------------------------------------------
__global__ __launch_bounds__(256) void prep_pack(const float* __restrict__ S,
                                                 const float* __restrict__ Wfc,
                                                 unsigned short* __restrict__ Spack,
                                                 unsigned short* __restrict__ Wp)
{
    int tid = blockIdx.x * 256 + threadIdx.x;   // 0..90111
    if (tid < 65536) {
        int j = tid & 7, l = (tid >> 3) & 63, nf = (tid >> 9) & 3, ks = tid >> 11;
        int k = ks * 32 + (l >> 4) * 8 + j;
        int d = nf * 16 + (l & 15);
        Spack[tid] = f2bf(S[k * 64 + d]);
    } else {
        int t2 = tid - 65536;                   // 0..24575
        int j = t2 & 7, l = (t2 >> 3) & 63, ct = (t2 >> 9) & 7, kt = t2 >> 12;
        int k = kt * 32 + (l >> 4) * 8 + j;     // 0..191
        int col = ct * 16 + (l & 15);
        Wp[t2] = f2bf(Wfc[k * 128 + col]);
    }
}

// ---------------------------------------------------------------------------
// fused: per block of 16 rows:
//  phase 1: musum = T@S (bf16 MFMA), cnt = T@ones; 4 waves x K=256, LDS reduce
//  phase 2: mu = musum/cnt, gather q, a = df@Wdiff+b; build z (bf16, LDS),
//           p12/p13/p23 via shuffle reduce
//  phase 3: e = relu(z@Wfc[0:192] + p*Wfc[192:195] + bfc) via MFMA;
//           p = sigmoid(e@Wout + bout)
// ---------------------------------------------------------------------------
__global__ __launch_bounds__(256) void fused_kernel(
    const int* __restrict__ questions, const int* __restrict__ T,
    const float* __restrict__ dfeat, const float* __restrict__ Qemb,
    const float* __restrict__ Wdiff, const float* __restrict__ bdiff,
    const float* __restrict__ Wfc, const float* __restrict__ bfc,
    const float* __restrict__ Wout, const float* __restrict__ bout,
    const unsigned short* __restrict__ Spack, const unsigned short* __restrict__ Wp,
    float* __restrict__ out_e, float* __restrict__ out_p)
{
    __shared__ alignas(16) float accred[4][16][68];       // wave, row, dim (pad 68)
    __shared__ float cntred[4][16];
    __shared__ alignas(16) unsigned short zb[16][200];    // bf16 z rows (192 used)
    __shared__ float scal[16][3];                          // p12,p13,p23
    __shared__ float pacc[16][4];

    const int tid  = threadIdx.x;
    const int lane = tid & 63;
    const int wid  = tid >> 6;
    const int g    = lane >> 4;
    const int rl   = lane & 15;
    const int rb   = blockIdx.x * 16;

    // ---- phase 1: T @ S over this wave's K-quarter --------------------------
    f32x4 a0{}, a1{}, a2{}, a3{}, ac{};
    bf16x8 ones;
#pragma unroll
    for (int j = 0; j < 8; ++j) ones[j] = (short)0x3F80;

    const int* tp = T + (rb + rl) * 1024 + wid * 256 + g * 8;
    const unsigned short* sp = Spack + (size_t)wid * 8 * 2048 + lane * 8;

#pragma unroll
    for (int ks = 0; ks < 8; ++ks) {
        int4 t0 = *(const int4*)(tp + ks * 32);
        int4 t1 = *(const int4*)(tp + ks * 32 + 4);
        bf16x8 af;
        af[0] = t0.x ? (short)0x3F80 : (short)0;
        af[1] = t0.y ? (short)0x3F80 : (short)0;
        af[2] = t0.z ? (short)0x3F80 : (short)0;
        af[3] = t0.w ? (short)0x3F80 : (short)0;
        af[4] = t1.x ? (short)0x3F80 : (short)0;
        af[5] = t1.y ? (short)0x3F80 : (short)0;
        af[6] = t1.z ? (short)0x3F80 : (short)0;
        af[7] = t1.w ? (short)0x3F80 : (short)0;

        const unsigned short* s2 = sp + ks * 2048;
        bf16x8 b0 = *(const bf16x8*)(s2);
        bf16x8 b1 = *(const bf16x8*)(s2 + 512);
        bf16x8 b2 = *(const bf16x8*)(s2 + 1024);
        bf16x8 b3 = *(const bf16x8*)(s2 + 1536);

        a0 = __builtin_amdgcn_mfma_f32_16x16x32_bf16(af, b0, a0, 0, 0, 0);
        a1 = __builtin_amdgcn_mfma_f32_16x16x32_bf16(af, b1, a1, 0, 0, 0);
        a2 = __builtin_amdgcn_mfma_f32_16x16x32_bf16(af, b2, a2, 0, 0, 0);
        a3 = __builtin_amdgcn_mfma_f32_16x16x32_bf16(af, b3, a3, 0, 0, 0);
        ac = __builtin_amdgcn_mfma_f32_16x16x32_bf16(af, ones, ac, 0, 0, 0);
    }

    // D layout: col = lane&15, row = (lane>>4)*4 + r
#pragma unroll
    for (int r = 0; r < 4; ++r) {
        int row = g * 4 + r;
        accred[wid][row][rl]      = a0[r];
        accred[wid][row][16 + rl] = a1[r];
        accred[wid][row][32 + rl] = a2[r];
        accred[wid][row][48 + rl] = a3[r];
    }
    if (rl == 0) {
#pragma unroll
        for (int r = 0; r < 4; ++r) cntred[wid][g * 4 + r] = ac[r];
    }
    __syncthreads();

    // ---- phase 2: combine partials, build z (bf16) --------------------------
    {
        int r = tid >> 4, c16 = tid & 15, d0 = c16 * 4;
        float c = cntred[0][r] + cntred[1][r] + cntred[2][r] + cntred[3][r];
        float inv = 1.f / c;
        float4 m0 = *(const float4*)&accred[0][r][d0];
        float4 m1 = *(const float4*)&accred[1][r][d0];
        float4 m2 = *(const float4*)&accred[2][r][d0];
        float4 m3 = *(const float4*)&accred[3][r][d0];
        float mu[4];
        mu[0] = (m0.x + m1.x + m2.x + m3.x) * inv;
        mu[1] = (m0.y + m1.y + m2.y + m3.y) * inv;
        mu[2] = (m0.z + m1.z + m2.z + m3.z) * inv;
        mu[3] = (m0.w + m1.w + m2.w + m3.w) * inv;

        int qi = questions[rb + r];
        float4 q4 = *(const float4*)(Qemb + (size_t)qi * 64 + d0);
        float q[4] = {q4.x, q4.y, q4.z, q4.w};

        float f0 = dfeat[(rb + r) * 3 + 0];
        float f1 = dfeat[(rb + r) * 3 + 1];
        float f2 = dfeat[(rb + r) * 3 + 2];
        float aa[4];
#pragma unroll
        for (int d = 0; d < 4; ++d)
            aa[d] = bdiff[d0 + d] + f0 * Wdiff[d0 + d] + f1 * Wdiff[64 + d0 + d]
                  + f2 * Wdiff[128 + d0 + d];

        ushort4 qv, mv, av;
        qv.x = f2bf(q[0]);  qv.y = f2bf(q[1]);  qv.z = f2bf(q[2]);  qv.w = f2bf(q[3]);
        mv.x = f2bf(mu[0]); mv.y = f2bf(mu[1]); mv.z = f2bf(mu[2]); mv.w = f2bf(mu[3]);
        av.x = f2bf(aa[0]); av.y = f2bf(aa[1]); av.z = f2bf(aa[2]); av.w = f2bf(aa[3]);
        *(ushort4*)&zb[r][d0]       = qv;
        *(ushort4*)&zb[r][64 + d0]  = mv;
        *(ushort4*)&zb[r][128 + d0] = av;

        float s12 = 0.f, s13 = 0.f, s23 = 0.f;
#pragma unroll
        for (int d = 0; d < 4; ++d) {
            s12 += q[d] * mu[d];
            s13 += q[d] * aa[d];
            s23 += mu[d] * aa[d];
        }
#pragma unroll
        for (int off = 1; off < 16; off <<= 1) {
            s12 += __shfl_xor(s12, off);
            s13 += __shfl_xor(s13, off);
            s23 += __shfl_xor(s23, off);
        }
        if (c16 == 0) { scal[r][0] = s12; scal[r][1] = s13; scal[r][2] = s23; }
    }
    __syncthreads();

    // ---- phase 3: tail GEMM (K=192) + epilogue ------------------------------
    {
        bf16x8 afr[6];
#pragma unroll
        for (int kt = 0; kt < 6; ++kt)
            afr[kt] = *(const bf16x8*)&zb[rl][kt * 32 + g * 8];

        float pr0 = 0.f, pr1 = 0.f, pr2 = 0.f, pr3 = 0.f;
#pragma unroll
        for (int c2 = 0; c2 < 2; ++c2) {
            int ct = wid * 2 + c2;
            f32x4 e{};
            const unsigned short* wp = Wp + (size_t)ct * 512 + lane * 8;
#pragma unroll
            for (int kt = 0; kt < 6; ++kt) {
                bf16x8 bfr = *(const bf16x8*)(wp + (size_t)kt * 4096);
                e = __builtin_amdgcn_mfma_f32_16x16x32_bf16(afr[kt], bfr, e, 0, 0, 0);
            }
            int h = ct * 16 + rl;
            float w192 = Wfc[192 * 128 + h];
            float w193 = Wfc[193 * 128 + h];
            float w194 = Wfc[194 * 128 + h];
            float bb = bfc[h];
            float wo = Wout[h];
#pragma unroll
            for (int r = 0; r < 4; ++r) {
                int row = g * 4 + r;
                float ev = e[r] + bb + scal[row][0] * w192 + scal[row][1] * w193
                         + scal[row][2] * w194;
                ev = ev > 0.f ? ev : 0.f;
                out_e[(size_t)(rb + row) * 128 + h] = ev;
                float pc = ev * wo;
                if (r == 0) pr0 += pc; else if (r == 1) pr1 += pc;
                else if (r == 2) pr2 += pc; else pr3 += pc;
            }
        }
#pragma unroll
        for (int off = 1; off < 16; off <<= 1) {
            pr0 += __shfl_xor(pr0, off);
            pr1 += __shfl_xor(pr1, off);
            pr2 += __shfl_xor(pr2, off);
            pr3 += __shfl_xor(pr3, off);
        }
        if (rl == 0) {
            pacc[g * 4 + 0][wid] = pr0;
            pacc[g * 4 + 1][wid] = pr1;
            pacc[g * 4 + 2][wid] = pr2;
            pacc[g * 4 + 3][wid] = pr3;
        }
    }
    __syncthreads();
    if (tid < 16) {
        float v = pacc[tid][0] + pacc[tid][1] + pacc[tid][2] + pacc[tid][3] + bout[0];
        out_p[rb + tid] = 1.f / (1.f + expf(-v));
    }
}

// ---------------------------------------------------------------------------
extern "C" void kernel_launch(void* const* d_in, const int* in_sizes, int n_in,
                              void* d_out, int out_size, void* d_ws, size_t ws_size,
                              hipStream_t stream)
{
    const int*   questions = (const int*)d_in[0];
    const int*   T         = (const int*)d_in[1];
    const float* dfeat     = (const float*)d_in[2];
    const float* Qemb      = (const float*)d_in[3];
    const float* Semb      = (const float*)d_in[4];
    const float* Wdiff     = (const float*)d_in[5];
    const float* bdiff     = (const float*)d_in[6];
    const float* Wfc       = (const float*)d_in[7];
    const float* bfc       = (const float*)d_in[8];
    const float* Wout      = (const float*)d_in[9];
    const float* bout      = (const float*)d_in[10];

    char* ws = (char*)d_ws;
    unsigned short* Spack = (unsigned short*)ws;             // 128 KiB
    unsigned short* Wp    = (unsigned short*)(ws + 131072);  // 48 KiB

    float* out_e = (float*)d_out;
    float* out_p = out_e + (size_t)BATCH * HID;

    hipLaunchKernelGGL(prep_pack, dim3(352), dim3(256), 0, stream, Semb, Wfc, Spack, Wp);
    hipLaunchKernelGGL(fused_kernel, dim3(BATCH / 16), dim3(256), 0, stream,
                       questions, T, dfeat, Qemb, Wdiff, bdiff, Wfc, bfc, Wout, bout,
                       Spack, Wp, out_e, out_p);
}